// Round 9
// baseline (46.498 us; speedup 1.0000x reference)
//
#include <hip/hip_runtime.h>
#include <stdint.h>

// Problem constants
#define BB 1024
#define MM 128
#define KK 32
#define NEDGE (BB * MM * KK)   // 4194304
#define BPB 4                  // blocks per batch
#define ROWS_PER_WAVE (MM / (4 * BPB))  // 8
#define HALF (ROWS_PER_WAVE / 2)        // 4

typedef unsigned int uint2v __attribute__((ext_vector_type(2)));

// compare-exchange with direction folded into the key (complement trick):
// keep-min where (g & stride)==0, uniform for all lanes -> 5 shared masks.
// partner via ds_swizzle (LDS pipe), min/max VALU, select via cndmask on an
// SGPR-pair mask anchored outside the loop.
#define CEXS(K, ST, MSK)                                                      \
  { unsigned p_ = (unsigned)__builtin_amdgcn_ds_swizzle((int)(K), ((ST) << 10) | 0x1F); \
    unsigned mn_ = __builtin_elementwise_min((K), p_);                        \
    unsigned mx_ = __builtin_elementwise_max((K), p_);                        \
    asm("v_cndmask_b32 %0, %1, %2, %3" : "=v"(K) : "v"(mx_), "v"(mn_), "s"(MSK)); }

// min over {v[l], v[l^32]} — bitonic split across the 32-lane halves
static __device__ __forceinline__ unsigned minxor32(unsigned k) {
#if __has_builtin(__builtin_amdgcn_permlane32_swap)
    uint2v s = __builtin_amdgcn_permlane32_swap(k, k, false, false);
    return __builtin_elementwise_min(s.x, s.y);
#else
    unsigned p = (unsigned)__shfl_xor((int)k, 32, 64);
    return __builtin_elementwise_min(k, p);
#endif
}

// grid = BB*BPB blocks of 256 threads; each wave handles 8 rows, processed as
// 4 interleaved pairs (i, i+4) for ILP. Per row: 128 candidates (2/lane),
// key = (f32bits(max(d2,0)) & ~0x7F) | j.  Sort four 32-blocks with direction
// complement-folded; min(k0,k1) shuffle-free bitonic split; dual-clean (upper
// half complemented); permlane split; final clean.
__global__ __launch_bounds__(256, 4) void knn_edges_kernel(const float* __restrict__ pos,
                                                           float* __restrict__ out) {
    __shared__ float px[MM], py[MM], pz[MM], sqs[MM];
    const int blk = blockIdx.x;
    const int b = blk >> 2;            // blk / BPB
    const int sub = blk & (BPB - 1);
    const int tid = threadIdx.x;

    if (tid < MM) {
        const float* p = pos + (size_t)(b * MM + tid) * 3;
        float x = p[0], y = p[1], z = p[2];
        px[tid] = x; py[tid] = y; pz[tid] = z;
        sqs[tid] = __fadd_rn(__fadd_rn(__fmul_rn(x, x), __fmul_rn(y, y)), __fmul_rn(z, z));
    }
    __syncthreads();

    const int wave = tid >> 6;
    const int lane = tid & 63;
    const int g = lane & 31;
    const bool hi = lane >= 32;
    const unsigned upper = hi ? ~0u : 0u;

    // ---- the 5 comparator masks, anchored once into SGPR pairs ----
    unsigned long long m1  = 0x5555555555555555ull;
    unsigned long long m2  = 0x3333333333333333ull;
    unsigned long long m4  = 0x0F0F0F0F0F0F0F0Full;
    unsigned long long m8  = 0x00FF00FF00FF00FFull;
    unsigned long long m16 = 0x0000FFFF0000FFFFull;
    asm("" : "+s"(m1), "+s"(m2), "+s"(m4), "+s"(m8), "+s"(m16));

    // ---- per-lane direction-fold constants (k0: A asc|B desc build) ----
    // desc at size-group s  <=>  ((g&s)==0) == (lane>=32)
    auto dmask = [&](int s) -> unsigned {
        unsigned zer = ((g & s) == 0) ? ~0u : 0u;
        return ~(zer ^ upper);   // XNOR: equal -> ~0 (complement), else 0
    };
    const unsigned f2    = dmask(2);
    const unsigned nf2   = ~f2;
    const unsigned f4c   = dmask(4);
    const unsigned f8c   = dmask(8);
    const unsigned f16c  = dmask(16);
    const unsigned f32c  = dmask(32);
    const unsigned t24   = f2 ^ f4c;
    const unsigned t48   = f4c ^ f8c;
    const unsigned t816  = f8c ^ f16c;
    const unsigned t1632 = f16c ^ f32c;
    const unsigned nf32  = ~f32c;

    // per-lane candidate coordinates, hoisted across the row loop
    const int j0 = lane, j1 = lane + 64;
    const float xa = px[j0], ya = py[j0], za = pz[j0], qa = sqs[j0];
    const float xb = px[j1], yb = py[j1], zb = pz[j1], qb = sqs[j1];

    const int row0 = sub * (MM / BPB) + wave * ROWS_PER_WAVE;
    const float fbase = (float)(b * MM);   // exact in fp32

    // output streams (3 stores/lane/row):
    //  lanes <32 : pA=src (KK), pB=vec.x (3KK), pC=vec.y (3KK)
    //  lanes >=32: pA=dst (KK), pB=vec.z (3KK), pC=weight (KK)
    float* const vecbase = out + 3 * (size_t)NEDGE;
    const long e0 = (long)(b * MM + row0) * KK + g;
    float* pA = hi ? out + (size_t)NEDGE + e0 : out + e0;
    float* pB = vecbase + e0 * 3 + (hi ? 2 : 0);
    float* pC = hi ? out + 2 * (size_t)NEDGE + e0 : vecbase + e0 * 3 + 1;
    const int sC = hi ? KK : 3 * KK;   // per-row stride of the C stream
    const int oC = sC * HALF;          // row-b offset within the C stream

    for (int ii = 0; ii < HALF; ++ii) {
        const int ia = row0 + ii;
        const int ib = ia + HALF;

        // ---- candidate keys for both rows (entry complement folded in) ----
        const float xia = px[ia], yia = py[ia], zia = pz[ia], qia = sqs[ia];
        const float xib = px[ib], yib = py[ib], zib = pz[ib], qib = sqs[ib];

        float dot;
        dot = fmaf(xia, xa, fmaf(yia, ya, zia * za));
        unsigned K0a = ((__float_as_uint(fmaxf(fmaf(-2.0f, dot, qia + qa), 0.0f)) & 0xFFFFFF80u) | (unsigned)j0) ^ f2;
        dot = fmaf(xia, xb, fmaf(yia, yb, zia * zb));
        unsigned K1a = ((__float_as_uint(fmaxf(fmaf(-2.0f, dot, qia + qb), 0.0f)) & 0xFFFFFF80u) | (unsigned)j1) ^ nf2;
        dot = fmaf(xib, xa, fmaf(yib, ya, zib * za));
        unsigned K0b = ((__float_as_uint(fmaxf(fmaf(-2.0f, dot, qib + qa), 0.0f)) & 0xFFFFFF80u) | (unsigned)j0) ^ f2;
        dot = fmaf(xib, xb, fmaf(yib, yb, zib * zb));
        unsigned K1b = ((__float_as_uint(fmaxf(fmaf(-2.0f, dot, qib + qb), 0.0f)) & 0xFFFFFF80u) | (unsigned)j1) ^ nf2;

#define ST4(ST, MSK) CEXS(K0a, ST, MSK) CEXS(K1a, ST, MSK) CEXS(K0b, ST, MSK) CEXS(K1b, ST, MSK)
#define XOR4(V) K0a ^= (V); K1a ^= (V); K0b ^= (V); K1b ^= (V);

        // ---- phase 1: sort the four 32-blocks, direction-folded ----
        ST4(1, m1)
        XOR4(t24)
        ST4(2, m2) ST4(1, m1)
        XOR4(t48)
        ST4(4, m4) ST4(2, m2) ST4(1, m1)
        XOR4(t816)
        ST4(8, m8) ST4(4, m4) ST4(2, m2) ST4(1, m1)
        XOR4(t1632)
        ST4(16, m16) ST4(8, m8) ST4(4, m4) ST4(2, m2) ST4(1, m1)
#undef ST4
#undef XOR4

        // ---- exit complements + shuffle-free bitonic split + dual-clean ----
        unsigned Ca = (__builtin_elementwise_min(K0a ^ f32c, K1a ^ nf32)) ^ upper;
        unsigned Cb = (__builtin_elementwise_min(K0b ^ f32c, K1b ^ nf32)) ^ upper;

#define CS2(ST, MSK) CEXS(Ca, ST, MSK) CEXS(Cb, ST, MSK)
        CS2(16, m16) CS2(8, m8) CS2(4, m4) CS2(2, m2) CS2(1, m1)
#undef CS2

        // ---- split across halves, final ascending clean ----
        unsigned Ma = minxor32(Ca ^ upper);
        unsigned Mb = minxor32(Cb ^ upper);
#define MS2(ST, MSK) CEXS(Ma, ST, MSK) CEXS(Mb, ST, MSK)
        MS2(16, m16) MS2(8, m8) MS2(4, m4) MS2(2, m2) MS2(1, m1)
#undef MS2

        // ---- epilogue row a ----
        {
            const bool taken = Ma < 0x41C80000u;   // d2 < 25.0
            const int j = (int)(Ma & 127u);
            const int sel = taken ? j : ia;
            float dxv = __fsub_rn(px[sel], xia);
            float dyv = __fsub_rn(py[sel], yia);
            float dzv = __fsub_rn(pz[sel], zia);
            float w = sqrtf(fmaf(dzv, dzv, fmaf(dyv, dyv, dxv * dxv)));
            const float fsrc = fbase + (float)sel;
            const float fnode = fbase + (float)ia;
            pA[0] = hi ? fnode : fsrc;
            pB[0] = hi ? dzv : dxv;
            pC[0] = hi ? w : dyv;
        }
        // ---- epilogue row b (immediate/precomputed offsets) ----
        {
            const bool taken = Mb < 0x41C80000u;
            const int j = (int)(Mb & 127u);
            const int sel = taken ? j : ib;
            float dxv = __fsub_rn(px[sel], xib);
            float dyv = __fsub_rn(py[sel], yib);
            float dzv = __fsub_rn(pz[sel], zib);
            float w = sqrtf(fmaf(dzv, dzv, fmaf(dyv, dyv, dxv * dxv)));
            const float fsrc = fbase + (float)sel;
            const float fnode = fbase + (float)ib;
            pA[HALF * KK] = hi ? fnode : fsrc;
            pB[HALF * 3 * KK] = hi ? dzv : dxv;
            pC[oC] = hi ? w : dyv;
        }
        pA += KK; pB += 3 * KK; pC += sC;
    }
}

extern "C" void kernel_launch(void* const* d_in, const int* in_sizes, int n_in,
                              void* d_out, int out_size, void* d_ws, size_t ws_size,
                              hipStream_t stream) {
    const float* pos = (const float*)d_in[0];
    float* out = (float*)d_out;
    hipLaunchKernelGGL(knn_edges_kernel, dim3(BB * BPB), dim3(256), 0, stream, pos, out);
}